// Round 2
// baseline (150.121 us; speedup 1.0000x reference)
//
#include <hip/hip_runtime.h>
#include <math.h>

// Filtered Back Projection, B=2, A=181, L=512, P=1024.
// ws layout (floats):
//   [0,1024)        filt
//   [1024,2048)     hr (real impulse response)
//   [2048,2229)     cth = cos(angle + pi/2)
//   [2304,2485)     sth = sin(angle + pi/2)
//   [2560,3072)     coef (f[odd] values)
//   [3072,4096)     tw: cos(2*pi*r/1024), r=0..1023
//   [4096,189440)   sino_f planar: [b][a][pos]
#define OFF_FILT 0
#define OFF_HR   1024
#define OFF_CTH  2048
#define OFF_STH  2304
#define OFF_COEF 2560
#define OFF_TW   3072
#define OFF_SF   4096
#define PLANE    92672      // 181*512
#define TWO_PI   6.283185307179586
#define PI_D     3.14159265358979323846

// ---------------- init: twiddle table, filter coefs, angle trig ------------
__global__ __launch_bounds__(256) void k_init(const float* __restrict__ angles,
                                              float* __restrict__ ws) {
  const int t = threadIdx.x;
#pragma unroll
  for (int q = 0; q < 4; q++) {
    int idx = t + 256 * q;
    ws[OFF_TW + idx] = (float)cos((double)idx * (TWO_PI / 1024.0));
  }
#pragma unroll
  for (int q = 0; q < 2; q++) {
    int tt = t + 256 * q;
    int n = (tt < 256) ? (2 * tt + 1) : (1023 - 2 * tt);
    double pin = PI_D * (double)n;
    ws[OFF_COEF + tt] = (float)(-1.0 / (pin * pin));
  }
  if (t < 181) {
    float th = angles[t] + 1.5707963267948966f;
    ws[OFF_CTH + t] = cosf(th);
    ws[OFF_STH + t] = sinf(th);
  }
}

// ---------------- filt[k] = ramp[k] * hann_shift[k], via table -------------
// ramp[k] = 0.5 + 2*sum_{tt<512} coef[tt]*cos(2*pi*((2tt+1)*k mod 1024)/1024)
__global__ __launch_bounds__(64) void k_filt(float* __restrict__ ws) {
  __shared__ float tws[1024];
  __shared__ float cfs[512];
  const int t = threadIdx.x;
  const float4* twg = (const float4*)(ws + OFF_TW);
  const float4* cfg = (const float4*)(ws + OFF_COEF);
#pragma unroll
  for (int q = 0; q < 4; q++) ((float4*)tws)[t + 64 * q] = twg[t + 64 * q];
#pragma unroll
  for (int q = 0; q < 2; q++) ((float4*)cfs)[t + 64 * q] = cfg[t + 64 * q];
  __syncthreads();
  const int k = blockIdx.x * 64 + t;
  const int step = (2 * k) & 1023;
  int r = k;                       // phase of first odd term: (2*0+1)*k
  float acc = 0.f;
#pragma unroll 4
  for (int tt = 0; tt < 512; tt++) {
    acc = fmaf(cfs[tt], tws[r], acc);
    r = (r + step) & 1023;
  }
  double ramp = 0.5 + 2.0 * (double)acc;
  int ks = (k + 512) & 1023;       // fftshift
  double hann = 0.5 - 0.5 * cos((double)ks * (TWO_PI / 1023.0));  // np.hanning
  ws[OFF_FILT + k] = (float)(ramp * hann);
}

// ---------------- hr[m] = (1/P) sum_k filt[k] cos(2*pi*k*m/P) --------------
// Re(ifft) is even in m: compute m in [0,512], mirror to 1024-m.
__global__ __launch_bounds__(64) void k_hr(float* __restrict__ ws) {
  __shared__ float tws[1024];
  __shared__ float fls[1024];
  const int t = threadIdx.x;
  const float4* twg = (const float4*)(ws + OFF_TW);
  const float4* flg = (const float4*)(ws + OFF_FILT);
#pragma unroll
  for (int q = 0; q < 4; q++) {
    ((float4*)tws)[t + 64 * q] = twg[t + 64 * q];
    ((float4*)fls)[t + 64 * q] = flg[t + 64 * q];
  }
  __syncthreads();
  const int m = blockIdx.x * 64 + t;
  if (m <= 512) {
    int r = 0;
    float acc = 0.f;
#pragma unroll 4
    for (int k = 0; k < 1024; k++) {
      acc = fmaf(fls[k], tws[r], acc);
      r = (r + m) & 1023;
    }
    float v = acc * (1.0f / 1024.0f);
    ws[OFF_HR + m] = v;
    ws[OFF_HR + ((1024 - m) & 1023)] = v;
  }
}

// ---------------- row-wise circular convolution with hr --------------------
__global__ __launch_bounds__(64) void k_conv(const float* __restrict__ sino,
                                             float* __restrict__ ws) {
  __shared__ float s_s[512];
  __shared__ float s_hr[1024];
  const int t = threadIdx.x;
  const int row = blockIdx.x;       // 0..361 == b*181 + a
  const float4* src4 = (const float4*)(sino + (size_t)row * 512);
  float4* ss4 = (float4*)s_s;
  ss4[t] = src4[t];
  ss4[t + 64] = src4[t + 64];
  const float4* hr4 = (const float4*)(ws + OFF_HR);
  float4* sh4 = (float4*)s_hr;
#pragma unroll
  for (int q = 0; q < 4; q++) sh4[t + 64 * q] = hr4[t + 64 * q];
  __syncthreads();

  const int base = t * 8;
  float acc[8] = {0.f, 0.f, 0.f, 0.f, 0.f, 0.f, 0.f, 0.f};
  const float4* SH = (const float4*)s_hr;
  const float4* SS = (const float4*)s_s;
  for (int j8 = 0; j8 < 512; j8 += 8) {
    float4 sva = SS[j8 >> 2];
    float4 svb = SS[(j8 >> 2) + 1];
    int w = base - j8;
    float4 h0 = SH[((w - 8) & 1023) >> 2];
    float4 h1 = SH[((w - 4) & 1023) >> 2];
    float4 h2 = SH[(w & 1023) >> 2];
    float4 h3 = SH[((w + 4) & 1023) >> 2];
    float qq[16] = {h0.x, h0.y, h0.z, h0.w, h1.x, h1.y, h1.z, h1.w,
                    h2.x, h2.y, h2.z, h2.w, h3.x, h3.y, h3.z, h3.w};
    float sv[8] = {sva.x, sva.y, sva.z, sva.w, svb.x, svb.y, svb.z, svb.w};
#pragma unroll
    for (int jj = 0; jj < 8; jj++)
#pragma unroll
      for (int m = 0; m < 8; m++)
        acc[m] = fmaf(sv[jj], qq[8 + m - jj], acc[m]);   // hr[(i-j)&1023]
  }
  float* dst = ws + OFF_SF + (size_t)row * 512 + base;
  ((float4*)dst)[0] = make_float4(acc[0], acc[1], acc[2], acc[3]);
  ((float4*)dst)[1] = make_float4(acc[4], acc[5], acc[6], acc[7]);
}

// ---------------- zero the output (atomic accumulation target) -------------
__global__ __launch_bounds__(256) void k_zero(float* __restrict__ out) {
  ((float4*)out)[blockIdx.x * 256 + threadIdx.x] =
      make_float4(0.f, 0.f, 0.f, 0.f);
}

// ---------------- backprojection -------------------------------------------
// grid (512, 2): blockIdx.x = output row i, blockIdx.y = angle half.
// Rows staged as interleaved {img0,img1} float2 entries with duplicate
// guard entries: entry e = tap position e-1; entry0 = pos0, entries 513/514
// = pos511. Then b=clamp(i0+1,0,513) gives both lerp taps as adjacent
// entries (one ds_read2_b64) with reference clip semantics and zero weights
// exactly matching the reference's bounds tests.
#define CHUNK 9
#define ROWE 516
__global__ __launch_bounds__(512) void k_bp(const float* __restrict__ ws,
                                            const int* __restrict__ circ,
                                            float* __restrict__ out) {
  __shared__ float2 srow[CHUNK * ROWE];   // 37152 B -> 4 blocks/CU
  const int j = threadIdx.x;
  const int i = blockIdx.x;
  const int abase = blockIdx.y * 91;
  const int acnt = min(91, 181 - abase);
  const float xc = (float)(i - 256);
  const float yc = (float)(j - 256);
  const float* __restrict__ cth = ws + OFF_CTH;
  const float* __restrict__ sth = ws + OFF_STH;
  const float* __restrict__ P0 = ws + OFF_SF;
  const float* __restrict__ P1 = ws + OFF_SF + PLANE;
  float acc0 = 0.f, acc1 = 0.f;

  for (int a0 = 0; a0 < acnt; a0 += CHUNK) {
    const int nv = min(CHUNK, acnt - a0);
    __syncthreads();
    for (int e = j; e < nv * 128; e += 512) {
      int r = e >> 7;
      int p = (e & 127) << 2;
      size_t g = (size_t)(abase + a0 + r) * 512 + p;
      float4 v0 = *(const float4*)(P0 + g);
      float4 v1 = *(const float4*)(P1 + g);
      float2* d = &srow[r * ROWE + 1 + p];
      d[0] = make_float2(v0.x, v1.x);
      d[1] = make_float2(v0.y, v1.y);
      d[2] = make_float2(v0.z, v1.z);
      d[3] = make_float2(v0.w, v1.w);
    }
    for (int e = j; e < nv; e += 512) {
      size_t g = (size_t)(abase + a0 + e) * 512;
      float2 L = make_float2(P0[g], P1[g]);
      float2 R = make_float2(P0[g + 511], P1[g + 511]);
      srow[e * ROWE + 0] = L;
      srow[e * ROWE + 513] = R;
      srow[e * ROWE + 514] = R;
    }
    __syncthreads();
    for (int r = 0; r < nv; r++) {
      const int a = abase + a0 + r;
      const float c = cth[a];
      const float s = sth[a];
      float u = fmaf(xc, c, fmaf(yc, s, 255.5f));
      float fl = floorf(u);
      float fr = u - fl;
      int i0 = (int)fl;
      float w0 = ((unsigned)i0 < 512u) ? (1.0f - fr) : 0.0f;
      float w1 = ((unsigned)(i0 + 1) < 512u) ? fr : 0.0f;
      int b = min(max(i0 + 1, 0), 513);
      const float2* rp = &srow[r * ROWE];
      float2 t0 = rp[b];
      float2 t1 = rp[b + 1];
      acc0 = fmaf(w0, t0.x, fmaf(w1, t1.x, acc0));
      acc1 = fmaf(w0, t0.y, fmaf(w1, t1.y, acc1));
    }
  }
  const int dx = j - 256, dy = i - 256;
  const bool msk = (circ[0] != 0) && (dx * dx + dy * dy > 65536);
  if (!msk) {
    const size_t o = (size_t)i * 512 + j;
    atomicAdd(&out[o], acc0);
    atomicAdd(&out[262144 + o], acc1);
  }
}

extern "C" void kernel_launch(void* const* d_in, const int* in_sizes, int n_in,
                              void* d_out, int out_size, void* d_ws, size_t ws_size,
                              hipStream_t stream) {
  const float* sino = (const float*)d_in[0];    // (2,181,512) f32
  const float* angles = (const float*)d_in[1];  // (181,) f32
  const int* circ = (const int*)d_in[2];        // scalar int
  float* ws = (float*)d_ws;                     // ~758 KB used
  float* out = (float*)d_out;                   // (2,512,512) f32

  hipLaunchKernelGGL(k_init, dim3(1),    dim3(256), 0, stream, angles, ws);
  hipLaunchKernelGGL(k_filt, dim3(16),   dim3(64),  0, stream, ws);
  hipLaunchKernelGGL(k_hr,   dim3(9),    dim3(64),  0, stream, ws);
  hipLaunchKernelGGL(k_conv, dim3(362),  dim3(64),  0, stream, sino, ws);
  hipLaunchKernelGGL(k_zero, dim3(512),  dim3(256), 0, stream, out);
  hipLaunchKernelGGL(k_bp,   dim3(512, 2), dim3(512), 0, stream, ws, circ, out);
}

// Round 3
// 114.043 us; speedup vs baseline: 1.3164x; 1.3164x over previous
//
#include <hip/hip_runtime.h>
#include <math.h>

// Filtered Back Projection, B=2, A=181, L=512, P=1024.
// ws layout (floats):
//   [0,1024)        filt
//   [1024,2048)     hr (real impulse response)
//   [2048,2229)     cth = cos(angle + pi/2)
//   [2304,2485)     sth = sin(angle + pi/2)
//   [4096,189440)   sino_f planar: [b][a][pos]
#define OFF_FILT 0
#define OFF_HR   1024
#define OFF_CTH  2048
#define OFF_STH  2304
#define OFF_SF   4096
#define PLANE    92672      // 181*512

// cos(2*pi*x) -- v_cos_f32 takes revolutions
__device__ __forceinline__ float cos2pi(float x) {
  return __builtin_amdgcn_cosf(x);
}

// ---- filt[k] = ramp[k]*hann_shift[k]; wave-per-output, v_cos phases -------
// ramp[k] = 0.5 + 2*sum_{tt<512} coef[tt]*cos(2*pi*((2tt+1)*k mod 1024)/1024)
__global__ __launch_bounds__(256) void k_filt(const float* __restrict__ angles,
                                              float* __restrict__ ws) {
  const int t = threadIdx.x & 63;
  const int k = blockIdx.x * 4 + (threadIdx.x >> 6);   // 0..1023
  float acc = 0.f;
#pragma unroll
  for (int q = 0; q < 8; q++) {
    int tt = t + 64 * q;
    int n = (tt < 256) ? (2 * tt + 1) : (1023 - 2 * tt);
    float pin = 3.14159265358979f * (float)n;
    float cf = -1.0f / (pin * pin);
    int r = ((2 * tt + 1) * k) & 1023;
    acc = fmaf(cf, cos2pi((float)r * (1.0f / 1024.0f)), acc);
  }
#pragma unroll
  for (int o = 32; o; o >>= 1) acc += __shfl_down(acc, o, 64);
  if (t == 0) {
    float ramp = 0.5f + 2.0f * acc;
    int ks = (k + 512) & 1023;                         // fftshift
    float hann = 0.5f - 0.5f * cos2pi((float)ks * (1.0f / 1023.0f));
    ws[OFF_FILT + k] = ramp * hann;
  }
  if (blockIdx.x == 0 && threadIdx.x < 181) {          // angle trig
    float th = angles[threadIdx.x] + 1.5707963267948966f;
    ws[OFF_CTH + threadIdx.x] = cosf(th);
    ws[OFF_STH + threadIdx.x] = sinf(th);
  }
}

// ---- hr[m] = (1/1024) sum_k filt[k] cos(2*pi*k*m/1024); wave-per-output ---
__global__ __launch_bounds__(256) void k_hr(float* __restrict__ ws) {
  const int t = threadIdx.x & 63;
  const int m = blockIdx.x * 4 + (threadIdx.x >> 6);   // 0..1023
  float acc = 0.f;
  int r = (t * m) & 1023;
  const int step = (64 * m) & 1023;
#pragma unroll
  for (int q = 0; q < 16; q++) {
    acc = fmaf(ws[OFF_FILT + t + 64 * q],
               cos2pi((float)r * (1.0f / 1024.0f)), acc);
    r = (r + step) & 1023;
  }
#pragma unroll
  for (int o = 32; o; o >>= 1) acc += __shfl_down(acc, o, 64);
  if (t == 0) ws[OFF_HR + m] = acc * (1.0f / 1024.0f);
}

// ---- row circular conv: grid (362 rows, 2 halves), 64 thr x 4 outputs -----
__global__ __launch_bounds__(64) void k_conv(const float* __restrict__ sino,
                                             float* __restrict__ ws) {
  __shared__ float s_s[512];
  __shared__ float s_hr[1024];
  const int t = threadIdx.x;
  const int row = blockIdx.x;       // 0..361 == b*181 + a
  const float4* src4 = (const float4*)(sino + (size_t)row * 512);
  float4* ss4 = (float4*)s_s;
  ss4[t] = src4[t];
  ss4[t + 64] = src4[t + 64];
  const float4* hr4 = (const float4*)(ws + OFF_HR);
  float4* sh4 = (float4*)s_hr;
#pragma unroll
  for (int q = 0; q < 4; q++) sh4[t + 64 * q] = hr4[t + 64 * q];
  __syncthreads();

  const int base = blockIdx.y * 256 + t * 4;   // 4 output positions
  float acc[4] = {0.f, 0.f, 0.f, 0.f};
  const float4* SH = (const float4*)s_hr;
  const float4* SS = (const float4*)s_s;
  for (int j8 = 0; j8 < 512; j8 += 8) {
    float4 sva = SS[j8 >> 2];
    float4 svb = SS[(j8 >> 2) + 1];
    int w = base - j8;
    float4 h0 = SH[((w - 8) & 1023) >> 2];
    float4 h1 = SH[((w - 4) & 1023) >> 2];
    float4 h2 = SH[(w & 1023) >> 2];
    float qq[12] = {h0.x, h0.y, h0.z, h0.w, h1.x, h1.y,
                    h1.z, h1.w, h2.x, h2.y, h2.z, h2.w};
    float sv[8] = {sva.x, sva.y, sva.z, sva.w, svb.x, svb.y, svb.z, svb.w};
#pragma unroll
    for (int jj = 0; jj < 8; jj++)
#pragma unroll
      for (int m = 0; m < 4; m++)
        acc[m] = fmaf(sv[jj], qq[8 + m - jj], acc[m]);   // hr[(base+m-j)&1023]
  }
  float* dst = ws + OFF_SF + (size_t)row * 512 + base;
  *(float4*)dst = make_float4(acc[0], acc[1], acc[2], acc[3]);
}

// ---- zero the output (atomic accumulation target) -------------------------
__global__ __launch_bounds__(256) void k_zero(float* __restrict__ out) {
  ((float4*)out)[blockIdx.x * 256 + threadIdx.x] =
      make_float4(0.f, 0.f, 0.f, 0.f);
}

// ---- backprojection -------------------------------------------------------
// grid (512, 2): x = output row i, y = angle half. Staged rows are padded
// with zero guards covering the full i0 range [-108, 620): OOB taps read 0,
// exactly matching the reference's zeroed weights -> no bounds tests, no
// clamps in the inner loop. One float2 {img0,img1} per position.
#define PAD   108
#define ROWE  728          // PAD + 512 + 108
#define CHUNK 6            // 6*728*8 = 34944 B LDS -> 4 blocks/CU
__global__ __launch_bounds__(512) void k_bp(const float* __restrict__ ws,
                                            const int* __restrict__ circ,
                                            float* __restrict__ out) {
  __shared__ float2 srow[CHUNK * ROWE];
  const int j = threadIdx.x;
  const int i = blockIdx.x;
  const int abase = blockIdx.y * 91;
  const int acnt = min(91, 181 - abase);
  const float xc = (float)(i - 256);
  const float yc = (float)(j - 256);
  const float* __restrict__ cth = ws + OFF_CTH;
  const float* __restrict__ sth = ws + OFF_STH;
  const float* __restrict__ P0 = ws + OFF_SF;
  const float* __restrict__ P1 = ws + OFF_SF + PLANE;
  float acc0 = 0.f, acc1 = 0.f;

  // zero the guard bands once; interior is rewritten every chunk
  const float2 z2 = make_float2(0.f, 0.f);
#pragma unroll
  for (int r = 0; r < CHUNK; r++) {
    if (j < PAD) srow[r * ROWE + j] = z2;
    if (j < ROWE - PAD - 512) srow[r * ROWE + PAD + 512 + j] = z2;
  }

  for (int a0 = 0; a0 < acnt; a0 += CHUNK) {
    const int nv = min(CHUNK, acnt - a0);
    __syncthreads();
    for (int r = 0; r < nv; r++) {     // one float2 per lane: conflict-free
      size_t g = (size_t)(abase + a0 + r) * 512 + j;
      srow[r * ROWE + PAD + j] = make_float2(P0[g], P1[g]);
    }
    __syncthreads();
    for (int r = 0; r < nv; r++) {
      const int a = abase + a0 + r;
      const float c = cth[a];          // uniform -> scalar loads
      const float s = sth[a];
      float u = fmaf(xc, c, fmaf(yc, s, 255.5f + (float)PAD));
      float fl = floorf(u);
      float fr = u - fl;
      int b = (int)fl;                 // in [1, 725] by construction
      const float2* rp = &srow[r * ROWE];
      float2 t0 = rp[b];
      float2 t1 = rp[b + 1];           // ds_read2_b64 pair
      float w0 = 1.0f - fr;
      acc0 = fmaf(w0, t0.x, fmaf(fr, t1.x, acc0));
      acc1 = fmaf(w0, t0.y, fmaf(fr, t1.y, acc1));
    }
  }
  const int dx = j - 256, dy = i - 256;
  const bool msk = (circ[0] != 0) && (dx * dx + dy * dy > 65536);
  if (!msk) {
    const size_t o = (size_t)i * 512 + j;
    atomicAdd(&out[o], acc0);
    atomicAdd(&out[262144 + o], acc1);
  }
}

extern "C" void kernel_launch(void* const* d_in, const int* in_sizes, int n_in,
                              void* d_out, int out_size, void* d_ws, size_t ws_size,
                              hipStream_t stream) {
  const float* sino = (const float*)d_in[0];    // (2,181,512) f32
  const float* angles = (const float*)d_in[1];  // (181,) f32
  const int* circ = (const int*)d_in[2];        // scalar int
  float* ws = (float*)d_ws;                     // ~758 KB used
  float* out = (float*)d_out;                   // (2,512,512) f32

  hipLaunchKernelGGL(k_filt, dim3(256),    dim3(256), 0, stream, angles, ws);
  hipLaunchKernelGGL(k_hr,   dim3(256),    dim3(256), 0, stream, ws);
  hipLaunchKernelGGL(k_conv, dim3(362, 2), dim3(64),  0, stream, sino, ws);
  hipLaunchKernelGGL(k_zero, dim3(512),    dim3(256), 0, stream, out);
  hipLaunchKernelGGL(k_bp,   dim3(512, 2), dim3(512), 0, stream, ws, circ, out);
}

// Round 4
// 95.044 us; speedup vs baseline: 1.5795x; 1.1999x over previous
//
#include <hip/hip_runtime.h>
#include <math.h>

// Filtered Back Projection, B=2, A=181, L=512, P=1024.
// ws layout (floats):
//   [0,1024)        filt
//   [1024,2048)     hr (real impulse response)
//   [2048,2229)     cth = cos(angle + pi/2)
//   [2304,2485)     sth = sin(angle + pi/2)
//   [4096,189440)   sino_f interleaved: [a][pos][{img0,img1}]  (181*512*2)
#define OFF_FILT 0
#define OFF_HR   1024
#define OFF_CTH  2048
#define OFF_STH  2304
#define OFF_SF   4096

// cos(2*pi*x) -- v_cos_f32 takes revolutions
__device__ __forceinline__ float cos2pi(float x) {
  return __builtin_amdgcn_cosf(x);
}

// ---- filt[k] = ramp[k]*hann_shift[k]; wave-per-output, v_cos phases -------
// Also zeroes d_out (atomic accumulation target for k_bp).
__global__ __launch_bounds__(256) void k_filt(const float* __restrict__ angles,
                                              float* __restrict__ ws,
                                              float* __restrict__ out) {
  const int t = threadIdx.x & 63;
  const int k = blockIdx.x * 4 + (threadIdx.x >> 6);   // 0..1023
  float acc = 0.f;
#pragma unroll
  for (int q = 0; q < 8; q++) {
    int tt = t + 64 * q;
    int n = (tt < 256) ? (2 * tt + 1) : (1023 - 2 * tt);
    float pin = 3.14159265358979f * (float)n;
    float cf = -1.0f / (pin * pin);
    int r = ((2 * tt + 1) * k) & 1023;
    acc = fmaf(cf, cos2pi((float)r * (1.0f / 1024.0f)), acc);
  }
#pragma unroll
  for (int o = 32; o; o >>= 1) acc += __shfl_down(acc, o, 64);
  if (t == 0) {
    float ramp = 0.5f + 2.0f * acc;
    int ks = (k + 512) & 1023;                         // fftshift
    float hann = 0.5f - 0.5f * cos2pi((float)ks * (1.0f / 1023.0f));
    ws[OFF_FILT + k] = ramp * hann;
  }
  if (blockIdx.x == 0 && threadIdx.x < 181) {          // angle trig
    float th = angles[threadIdx.x] + 1.5707963267948966f;
    ws[OFF_CTH + threadIdx.x] = cosf(th);
    ws[OFF_STH + threadIdx.x] = sinf(th);
  }
  // zero d_out: 2*512*512 floats = 131072 float4, 65536 threads x 2
  const float4 z4 = make_float4(0.f, 0.f, 0.f, 0.f);
  float4* o4 = (float4*)out;
  int idx = blockIdx.x * 256 + threadIdx.x;
  o4[idx] = z4;
  o4[idx + 65536] = z4;
}

// ---- hr[m] = (1/1024) sum_k filt[k] cos(2*pi*k*m/1024); wave-per-output ---
__global__ __launch_bounds__(256) void k_hr(float* __restrict__ ws) {
  const int t = threadIdx.x & 63;
  const int m = blockIdx.x * 4 + (threadIdx.x >> 6);   // 0..1023
  float acc = 0.f;
  int r = (t * m) & 1023;
  const int step = (64 * m) & 1023;
#pragma unroll
  for (int q = 0; q < 16; q++) {
    acc = fmaf(ws[OFF_FILT + t + 64 * q],
               cos2pi((float)r * (1.0f / 1024.0f)), acc);
    r = (r + step) & 1023;
  }
#pragma unroll
  for (int o = 32; o; o >>= 1) acc += __shfl_down(acc, o, 64);
  if (t == 0) ws[OFF_HR + m] = acc * (1.0f / 1024.0f);
}

// ---- row circular conv, BOTH planes per block, interleaved output ---------
// grid (181 angles, 2 position-halves), 64 thr x 4 positions x 2 images.
__global__ __launch_bounds__(64) void k_conv(const float* __restrict__ sino,
                                             float* __restrict__ ws) {
  __shared__ float s_s0[512];
  __shared__ float s_s1[512];
  __shared__ float s_hr[1024];
  const int t = threadIdx.x;
  const int a = blockIdx.x;         // 0..180
  const float4* r0 = (const float4*)(sino + (size_t)a * 512);
  const float4* r1 = (const float4*)(sino + (size_t)(181 + a) * 512);
  ((float4*)s_s0)[t] = r0[t];
  ((float4*)s_s0)[t + 64] = r0[t + 64];
  ((float4*)s_s1)[t] = r1[t];
  ((float4*)s_s1)[t + 64] = r1[t + 64];
  const float4* hr4 = (const float4*)(ws + OFF_HR);
#pragma unroll
  for (int q = 0; q < 4; q++) ((float4*)s_hr)[t + 64 * q] = hr4[t + 64 * q];
  __syncthreads();

  const int base = blockIdx.y * 256 + t * 4;   // 4 output positions
  float acc0[4] = {0.f, 0.f, 0.f, 0.f};
  float acc1[4] = {0.f, 0.f, 0.f, 0.f};
  const float4* SH = (const float4*)s_hr;
  const float4* S0 = (const float4*)s_s0;
  const float4* S1 = (const float4*)s_s1;
  for (int j8 = 0; j8 < 512; j8 += 8) {
    float4 sa0 = S0[j8 >> 2];
    float4 sb0 = S0[(j8 >> 2) + 1];
    float4 sa1 = S1[j8 >> 2];
    float4 sb1 = S1[(j8 >> 2) + 1];
    int w = base - j8;
    float4 h0 = SH[((w - 8) & 1023) >> 2];
    float4 h1 = SH[((w - 4) & 1023) >> 2];
    float4 h2 = SH[(w & 1023) >> 2];
    float qq[12] = {h0.x, h0.y, h0.z, h0.w, h1.x, h1.y,
                    h1.z, h1.w, h2.x, h2.y, h2.z, h2.w};
    float v0[8] = {sa0.x, sa0.y, sa0.z, sa0.w, sb0.x, sb0.y, sb0.z, sb0.w};
    float v1[8] = {sa1.x, sa1.y, sa1.z, sa1.w, sb1.x, sb1.y, sb1.z, sb1.w};
#pragma unroll
    for (int jj = 0; jj < 8; jj++) {
#pragma unroll
      for (int m = 0; m < 4; m++) {
        acc0[m] = fmaf(v0[jj], qq[8 + m - jj], acc0[m]);
        acc1[m] = fmaf(v1[jj], qq[8 + m - jj], acc1[m]);
      }
    }
  }
  // interleaved write: float index OFF_SF + a*1024 + base*2 + 2*p + img
  float* dst = ws + OFF_SF + (size_t)a * 1024 + base * 2;
  ((float4*)dst)[0] = make_float4(acc0[0], acc1[0], acc0[1], acc1[1]);
  ((float4*)dst)[1] = make_float4(acc0[2], acc1[2], acc0[3], acc1[3]);
}

// ---- backprojection -------------------------------------------------------
// grid (512, 2): x = output row i, y = angle half. Rows staged in LDS as
// float2 {img0,img1} per position with zero guard bands covering the full
// i0 range (OOB taps read 0 == reference's zeroed weights -> no bounds
// tests). Staging is software-pipelined: chunk c+1's global float4s are
// prefetched into registers while chunk c is being consumed; per thread per
// chunk exactly 2 global_load_dwordx4 + 2 ds_write_b128.
#define PAD   108
#define ROWE  728          // PAD + 512 + PAD
#define CHUNK 4            // 4*728*8 = 23296 B LDS -> 4 blocks/CU (wave cap)
__global__ __launch_bounds__(512) void k_bp(const float* __restrict__ ws,
                                            const int* __restrict__ circ,
                                            float* __restrict__ out) {
  __shared__ float2 srow[CHUNK * ROWE];
  const int j = threadIdx.x;
  const int i = blockIdx.x;
  const int abase = blockIdx.y * 91;
  const int acnt = min(91, 181 - abase);       // 91 or 90
  const float xc = (float)(i - 256);
  const float yc = (float)(j - 256);
  const float* __restrict__ cth = ws + OFF_CTH;
  const float* __restrict__ sth = ws + OFF_STH;
  float acc0 = 0.f, acc1 = 0.f;

  // zero guard bands once; interior rewritten every chunk
  const float2 z2 = make_float2(0.f, 0.f);
#pragma unroll
  for (int r = 0; r < CHUNK; r++) {
    if (j < PAD) srow[r * ROWE + j] = z2;
    if (j < ROWE - PAD - 512) srow[r * ROWE + PAD + 512 + j] = z2;
  }

  // staging slots: thread t owns float4 slots t and t+512 of each chunk
  // slot s -> row r = s>>8, pos p = (s&255)*2  (one float4 = 2 positions)
  const int r0 = j >> 8, r1 = r0 + 2;
  const int p0 = (j & 255) * 2;
  const int col = j & 255;
  const float4* __restrict__ G = (const float4*)(ws + OFF_SF);
  float4* SW0 = (float4*)&srow[r0 * ROWE + PAD + p0];
  float4* SW1 = (float4*)&srow[r1 * ROWE + PAD + p0];
  const int rowcap = abase + acnt - 1;

  int A = abase;
  float4 pre0 = G[min(A + r0, rowcap) * 256 + col];
  float4 pre1 = G[min(A + r1, rowcap) * 256 + col];

  for (int c = 0; c < 23; c++) {
    __syncthreads();                 // previous chunk fully consumed
    *SW0 = pre0;
    *SW1 = pre1;
    const int An = A + CHUNK;
    if (c < 22) {                    // prefetch next chunk (latency hidden)
      pre0 = G[min(An + r0, rowcap) * 256 + col];
      pre1 = G[min(An + r1, rowcap) * 256 + col];
    }
    __syncthreads();                 // writes visible
    const int nv = min(CHUNK, abase + acnt - A);
#pragma unroll
    for (int r = 0; r < CHUNK; r++) {
      if (r >= nv) break;
      const int a = A + r;
      const float c_ = cth[a];       // uniform -> scalar loads
      const float s_ = sth[a];
      float u = fmaf(xc, c_, fmaf(yc, s_, 255.5f + (float)PAD));
      float fl = floorf(u);
      float fr = u - fl;
      int b = (int)fl;               // in [1, 725] by construction
      const float2* rp = &srow[r * ROWE];
      float2 t0 = rp[b];
      float2 t1 = rp[b + 1];
      float w0 = 1.0f - fr;
      acc0 = fmaf(w0, t0.x, fmaf(fr, t1.x, acc0));
      acc1 = fmaf(w0, t0.y, fmaf(fr, t1.y, acc1));
    }
    A = An;
  }
  const int dx = j - 256, dy = i - 256;
  const bool msk = (circ[0] != 0) && (dx * dx + dy * dy > 65536);
  if (!msk) {
    const size_t o = (size_t)i * 512 + j;
    atomicAdd(&out[o], acc0);
    atomicAdd(&out[262144 + o], acc1);
  }
}

extern "C" void kernel_launch(void* const* d_in, const int* in_sizes, int n_in,
                              void* d_out, int out_size, void* d_ws, size_t ws_size,
                              hipStream_t stream) {
  const float* sino = (const float*)d_in[0];    // (2,181,512) f32
  const float* angles = (const float*)d_in[1];  // (181,) f32
  const int* circ = (const int*)d_in[2];        // scalar int
  float* ws = (float*)d_ws;                     // ~758 KB used
  float* out = (float*)d_out;                   // (2,512,512) f32

  hipLaunchKernelGGL(k_filt, dim3(256),    dim3(256), 0, stream, angles, ws, out);
  hipLaunchKernelGGL(k_hr,   dim3(256),    dim3(256), 0, stream, ws);
  hipLaunchKernelGGL(k_conv, dim3(181, 2), dim3(64),  0, stream, sino, ws);
  hipLaunchKernelGGL(k_bp,   dim3(512, 2), dim3(512), 0, stream, ws, circ, out);
}